// Round 13
// baseline (114.845 us; speedup 1.0000x reference)
//
#include <hip/hip_runtime.h>
#include <math.h>

// Problem constants (B=16, C=64, H=W=128)
#define NB 16
#define CC 64
#define HH 128
#define WW 128
#define NPIX (NB*CC*HH*WW)       // 16777216
#define WELEM (CC*CC*9)          // 36864

// conv tiling: 8 rows x 16 cols output per block, all 64 oc. halo 10x18.
#define TRR 8
#define TCC 16
#define HRR 10
#define HCC 18
#define HPX (HRR*HCC)            // 180 halo pixels
#define PL  (HH*WW)              // plane stride

// padded quantized-x tensor: [n][132 rows][130 cols][64 ic] int8
#define PYY 132
#define PXX 130
#define XQIMG (PYY*PXX*64)       // 1098240 B per image
#define XQTOT (NB*XQIMG)         // 17571840 B

// scal layout (dwords): s1 slots at [i*16], i=0..31 ; s2 slots at [512+i*32]
#define S2OFF 512

typedef __attribute__((ext_vector_type(4))) int   int32x4;
typedef __attribute__((ext_vector_type(8))) short short8_t;

// LDS activation layout (conv2): [pix][64B], 16B chunks XOR-swizzled.
__device__ __forceinline__ int lds_a(int pix, int q) {
    return pix * 64 + ((q ^ ((pix >> 1) & 3)) << 4);
}

__device__ __forceinline__ float read_s1(const unsigned* scal) {
    float m = 0.f;
    #pragma unroll
    for (int i = 0; i < 32; ++i) m = fmaxf(m, __uint_as_float(scal[i * 16]));
    return m + 1e-8f;
}

__device__ __forceinline__ float max4(float4 v) {
    return fmaxf(fmaxf(fabsf(v.x), fabsf(v.y)), fmaxf(fabsf(v.z), fabsf(v.w)));
}

// ---------------- kernel 1: fused global max|x| + DoReFa weight quant ----------------
// blocks 0..2047: absmax over x (8 float4/thread, tree, slotted atomics)
// blocks 2048..2079: weight quant, 16 blocks per tensor (slice-parallel tail).
__global__ __launch_bounds__(256) void k_reduce(const float* __restrict__ x,
                                                const float* __restrict__ w1,
                                                const float* __restrict__ w2,
                                                unsigned* __restrict__ scal,
                                                signed char* __restrict__ o1,
                                                signed char* __restrict__ o2) {
    __shared__ float red[4];
    const int tid = threadIdx.x;
    if (blockIdx.x < 2048) {
        const float4* x4 = (const float4*)x;
        const int base = blockIdx.x * 2048 + tid;
        float4 v0 = x4[base];
        float4 v1 = x4[base + 256];
        float4 v2 = x4[base + 512];
        float4 v3 = x4[base + 768];
        float4 v4 = x4[base + 1024];
        float4 v5 = x4[base + 1280];
        float4 v6 = x4[base + 1536];
        float4 v7 = x4[base + 1792];
        float a0 = fmaxf(max4(v0), max4(v1));
        float a1 = fmaxf(max4(v2), max4(v3));
        float a2 = fmaxf(max4(v4), max4(v5));
        float a3 = fmaxf(max4(v6), max4(v7));
        float m = fmaxf(fmaxf(a0, a1), fmaxf(a2, a3));
        #pragma unroll
        for (int o = 32; o; o >>= 1) m = fmaxf(m, __shfl_down(m, o, 64));
        if ((tid & 63) == 0) red[tid >> 6] = m;
        __syncthreads();
        if (tid == 0) {
            float v = fmaxf(fmaxf(red[0], red[1]), fmaxf(red[2], red[3]));
            atomicMax(&scal[(blockIdx.x & 31) * 16], __float_as_uint(v));
        }
    } else {
        const int wb = blockIdx.x - 2048;          // 0..31
        const int ten = wb >> 4;                   // 0 = w1, 1 = w2
        const int sl  = wb & 15;                   // slice: 4 oc per block
        const float* __restrict__ w = ten ? w2 : w1;
        signed char* __restrict__ w8 = ten ? o2 : o1;

        const float4* w4 = (const float4*)w;
        float m = 0.f;
        #pragma unroll
        for (int k = 0; k < 9; ++k) {
            float4 a = w4[tid + (k * 4 + 0) * 256];
            float4 b = w4[tid + (k * 4 + 1) * 256];
            float4 c = w4[tid + (k * 4 + 2) * 256];
            float4 d = w4[tid + (k * 4 + 3) * 256];
            m = fmaxf(m, fmaxf(fmaxf(max4(a), max4(b)), fmaxf(max4(c), max4(d))));
        }
        #pragma unroll
        for (int o = 32; o; o >>= 1) m = fmaxf(m, __shfl_down(m, o, 64));
        if ((tid & 63) == 0) red[tid >> 6] = m;
        __syncthreads();
        float mx = fmaxf(fmaxf(red[0], red[1]), fmaxf(red[2], red[3]));
        // max|tanh(w)| == tanh(max|w|)  (tanh monotone, odd)
        float inv = 1.f / (tanhf(mx) + 1e-8f);

        #pragma unroll
        for (int j = 0; j < 9; ++j) {
            int i = sl * 2304 + j * 256 + tid;
            float wt = tanhf(w[i]) * inv;                 // [-1, 1]
            float r  = rintf((wt + 1.f) * 1.5f);          // 0..3 (round-half-even)
            int oc = i / 576, rem = i % 576, ic = rem / 9, tap = rem % 9;
            // fragment: lane = (oc&15) | ((ic>>4)<<4); k-byte = ic&15
            int lane2 = (oc & 15) | ((ic >> 4) << 4);
            w8[(((oc >> 4) * 9 + tap) * 64 + lane2) * 16 + (ic & 15)] =
                (signed char)(int)(2.f * r - 3.f);
        }
    }
}

// ---------------- kernel 1b: quantize x -> padded pixel-major int8 ----------------
__global__ __launch_bounds__(256) void k_quantx(const float* __restrict__ x,
                                                const unsigned* __restrict__ scal,
                                                signed char* __restrict__ xq) {
    __shared__ signed char ldsA[64 * 68];
    __shared__ int ldsB[64 * 16];
    const int tid = threadIdx.x;
    const int n = blockIdx.z, y = blockIdx.y, s = blockIdx.x;
    const float inv_s1 = 1.f / read_s1(scal);

    {
        const int ic = tid >> 2, g = tid & 3;
        const float* __restrict__ src =
            x + (((size_t)n * CC + ic) * HH + y) * WW + s * 64 + g * 16;
        unsigned dw[4];
        #pragma unroll
        for (int q = 0; q < 4; ++q) {
            float4 v = *(const float4*)(src + q * 4);
            float e[4] = {v.x, v.y, v.z, v.w};
            unsigned d = 0;
            #pragma unroll
            for (int j = 0; j < 4; ++j) {
                int qq = (int)rintf(fminf(fmaxf(e[j] * inv_s1, -1.f), 1.f));
                d |= (unsigned)(qq & 255) << (8 * j);
            }
            dw[q] = d;
        }
        *(int4*)(ldsA + ic * 68 + g * 16) = *(const int4*)dw;
    }
    __syncthreads();
    #pragma unroll
    for (int i = 0; i < 4; ++i) {
        int idx = tid + i * 256;
        int d = idx & 15, p = idx >> 4;
        const signed char* a = ldsA + (d * 4) * 68 + p;
        unsigned b0 = (unsigned char)a[0];
        unsigned b1 = (unsigned char)a[68];
        unsigned b2 = (unsigned char)a[136];
        unsigned b3 = (unsigned char)a[204];
        ldsB[p * 16 + d] = (int)(b0 | (b1 << 8) | (b2 << 16) | (b3 << 24));
    }
    __syncthreads();
    signed char* dst = xq + ((size_t)n * PYY + (y + 1)) * (PXX * 64)
                          + (size_t)(1 + s * 64) * 64;
    ((int4*)dst)[tid] = ((const int4*)ldsB)[tid];
}

// ---------------- conv1: barrier-free streaming MFMA, 256-thr blocks ----------------
// Per wave: 2 rows x 16 cols x all 64 oc. acc = 2x4 int32x4 = 32 VGPR.
__global__ __launch_bounds__(256, 5) void k_conv1(
    const signed char* __restrict__ xq,
    const signed char* __restrict__ w8,
    const float* __restrict__ bias,       // b1 (for relu-max only)
    unsigned* __restrict__ scal,
    short* __restrict__ accout)
{
    __shared__ float redm[4];
    const int tid = threadIdx.x;
    const int n   = blockIdx.z;
    const int oy0 = blockIdx.y * TRR;
    const int ox0 = blockIdx.x * TCC;
    const float s1 = read_s1(scal);

    const int w     = tid >> 6;           // 0..3
    const int lane  = tid & 63;
    const int lq    = lane >> 4;
    const int lc    = lane & 15;
    const int rbase = w * 2;              // 2 rows per wave

    const signed char* __restrict__ A0 = xq + (size_t)n * XQIMG
        + ((size_t)(oy0 + rbase) * PXX + ox0 + lc) * 64 + lq * 16;
    const signed char* __restrict__ W0 = w8 + (size_t)lane * 16;

    int32x4 acc[2][4] = {};
    #pragma unroll 3
    for (int tap = 0; tap < 9; ++tap) {
        const int ky = tap / 3, kx = tap % 3;
        int32x4 b0 = *(const int32x4*)(W0 + (size_t)(0 * 9 + tap) * 1024);
        int32x4 b1 = *(const int32x4*)(W0 + (size_t)(1 * 9 + tap) * 1024);
        int32x4 b2 = *(const int32x4*)(W0 + (size_t)(2 * 9 + tap) * 1024);
        int32x4 b3 = *(const int32x4*)(W0 + (size_t)(3 * 9 + tap) * 1024);
        const signed char* ar = A0 + (ky * PXX + kx) * 64;
        #pragma unroll
        for (int j = 0; j < 2; ++j) {
            int32x4 a = *(const int32x4*)(ar + j * (PXX * 64));
            acc[j][0] = __builtin_amdgcn_mfma_i32_16x16x64_i8(a, b0, acc[j][0], 0, 0, 0);
            acc[j][1] = __builtin_amdgcn_mfma_i32_16x16x64_i8(a, b1, acc[j][1], 0, 0, 0);
            acc[j][2] = __builtin_amdgcn_mfma_i32_16x16x64_i8(a, b2, acc[j][2], 0, 0, 0);
            acc[j][3] = __builtin_amdgcn_mfma_i32_16x16x64_i8(a, b3, acc[j][3], 0, 0, 0);
        }
    }

    // epilogue: pixel-major int16 store + slotted atomic relu-max
    const float sc = s1 * (1.f / 3.f);
    float m2 = 0.f;
    #pragma unroll
    for (int j = 0; j < 2; ++j) {
        const int yy = oy0 + rbase + j;
        const size_t pbase = (((size_t)n * HH + yy) * WW + (ox0 + lq * 4)) * 64;
        #pragma unroll
        for (int g = 0; g < 4; ++g) {
            const float bo = bias[g * 16 + lc];
            #pragma unroll
            for (int e = 0; e < 4; ++e) {
                int v = acc[j][g][e];
                m2 = fmaxf(m2, sc * (float)v + bo);
                accout[pbase + (size_t)e * 64 + g * 16 + lc] = (short)v;
            }
        }
    }
    #pragma unroll
    for (int o = 32; o; o >>= 1) m2 = fmaxf(m2, __shfl_down(m2, o, 64));
    if (lane == 0) redm[w] = m2;
    __syncthreads();
    if (tid == 0) {
        float v = fmaxf(fmaxf(redm[0], redm[1]), fmaxf(redm[2], redm[3]));
        int slot = (blockIdx.x + blockIdx.y * 8 + blockIdx.z) & 7;
        atomicMax(&scal[S2OFF + slot * 32], __float_as_uint(v));
    }
}

// ---------------- conv2: binarize-stage (tiny LDS) + MFMA, 256-thr blocks ----------
__global__ __launch_bounds__(256, 5) void k_conv2(
    const float* __restrict__ x,
    const short* __restrict__ accin,      // pixel-major [n][y][x][64]
    const signed char* __restrict__ w8,
    const float* __restrict__ bias,       // b2
    const float* __restrict__ b1v,        // b1 (dequant of acc)
    const unsigned* __restrict__ scal,
    float* __restrict__ out)
{
    __shared__ signed char sA[HPX * 64] __attribute__((aligned(16)));   // 11520 B

    const int tid = threadIdx.x;
    const int n   = blockIdx.z;
    const int oy0 = blockIdx.y * TRR;
    const int ox0 = blockIdx.x * TCC;

    const float s1 = read_s1(scal);
    float mx = 0.f;
    #pragma unroll
    for (int i = 0; i < 8; ++i) mx = fmaxf(mx, __uint_as_float(scal[S2OFF + i * 32]));
    const float s2v = mx + 1e-8f;
    const float half_s2 = 0.5f * s2v;
    const float sc1 = s1 * (1.f / 3.f);

    // stage: one halo pixel per thread (180 tasks), 128B contiguous read
    if (tid < HPX) {
        const int r = tid / HCC, c = tid - r * HCC;
        const int y  = oy0 - 1 + r;
        const int xx = ox0 - 1 + c;
        unsigned pk[16];
        #pragma unroll
        for (int d = 0; d < 16; ++d) pk[d] = 0;
        if (y >= 0 && y < HH && xx >= 0 && xx < WW) {
            const short8_t* __restrict__ ap =
                (const short8_t*)(accin + (((size_t)n * HH + y) * WW + xx) * 64);
            #pragma unroll
            for (int k = 0; k < 8; ++k) {
                short8_t sv = ap[k];
                float4 bA = *(const float4*)(b1v + k * 8);
                float4 bB = *(const float4*)(b1v + k * 8 + 4);
                float ba[8] = {bA.x, bA.y, bA.z, bA.w, bB.x, bB.y, bB.z, bB.w};
                #pragma unroll
                for (int e = 0; e < 8; ++e) {
                    float fv = sc1 * (float)sv[e] + ba[e];
                    if (fv >= half_s2) pk[2 * k + (e >> 2)] |= 1u << ((e & 3) * 8);
                }
            }
        }
        #pragma unroll
        for (int q = 0; q < 4; ++q) {
            int4 wv;
            wv.x = (int)pk[4 * q];     wv.y = (int)pk[4 * q + 1];
            wv.z = (int)pk[4 * q + 2]; wv.w = (int)pk[4 * q + 3];
            *(int4*)(sA + lds_a(tid, q)) = wv;
        }
    }
    __syncthreads();

    const int w     = tid >> 6;
    const int lane  = tid & 63;
    const int lq    = lane >> 4;
    const int lc    = lane & 15;
    const int rbase = w * 2;
    const signed char* __restrict__ W0 = w8 + (size_t)lane * 16;

    int32x4 acc[2][4] = {};
    __builtin_amdgcn_s_setprio(1);
    #pragma unroll 3
    for (int tap = 0; tap < 9; ++tap) {
        const int ky = tap / 3, kx = tap % 3;
        int32x4 b0 = *(const int32x4*)(W0 + (size_t)(0 * 9 + tap) * 1024);
        int32x4 b1 = *(const int32x4*)(W0 + (size_t)(1 * 9 + tap) * 1024);
        int32x4 b2 = *(const int32x4*)(W0 + (size_t)(2 * 9 + tap) * 1024);
        int32x4 b3 = *(const int32x4*)(W0 + (size_t)(3 * 9 + tap) * 1024);
        #pragma unroll
        for (int j = 0; j < 2; ++j) {
            int pix = (rbase + j + ky) * HCC + kx + lc;
            int32x4 a = *(const int32x4*)(sA + lds_a(pix, lq));
            acc[j][0] = __builtin_amdgcn_mfma_i32_16x16x64_i8(a, b0, acc[j][0], 0, 0, 0);
            acc[j][1] = __builtin_amdgcn_mfma_i32_16x16x64_i8(a, b1, acc[j][1], 0, 0, 0);
            acc[j][2] = __builtin_amdgcn_mfma_i32_16x16x64_i8(a, b2, acc[j][2], 0, 0, 0);
            acc[j][3] = __builtin_amdgcn_mfma_i32_16x16x64_i8(a, b3, acc[j][3], 0, 0, 0);
        }
    }
    __builtin_amdgcn_s_setprio(0);

    const float sc = s2v * (1.f / 3.f);
    const size_t imgbase = (size_t)n * CC * PL;

    #pragma unroll
    for (int j = 0; j < 2; ++j) {
        const int yy = oy0 + rbase + j;
        const int xb = ox0 + lq * 4;
        #pragma unroll
        for (int g = 0; g < 4; ++g) {
            const int oc = g * 16 + lc;
            const float bo = bias[oc];
            size_t p = imgbase + (size_t)oc * PL + yy * WW + xb;
            float4 xa = *(const float4*)(x + p);
            float4 r;
            r.x = sc * (float)acc[j][g][0] + bo + xa.x;
            r.y = sc * (float)acc[j][g][1] + bo + xa.y;
            r.z = sc * (float)acc[j][g][2] + bo + xa.z;
            r.w = sc * (float)acc[j][g][3] + bo + xa.w;
            *(float4*)(out + p) = r;
        }
    }
}

extern "C" void kernel_launch(void* const* d_in, const int* in_sizes, int n_in,
                              void* d_out, int out_size, void* d_ws, size_t ws_size,
                              hipStream_t stream) {
    const float* x  = (const float*)d_in[0];
    const float* w1 = (const float*)d_in[1];
    const float* b1 = (const float*)d_in[2];
    const float* w2 = (const float*)d_in[3];
    const float* b2 = (const float*)d_in[4];
    float* out = (float*)d_out;

    // ws layout
    unsigned*    scal  = (unsigned*)d_ws;                  // s1 slots [i*16], s2 [512+i*32]
    signed char* w8_1  = (signed char*)d_ws + 4096;        // 36864 B
    signed char* w8_2  = w8_1 + WELEM;                     // 36864 B
    short*       acc16 = (short*)((char*)d_ws + 131072);   // 33.55 MB pixel-major
    // xq lives in d_out's scratch space: written by k_quantx, read only by
    // k_conv1, fully overwritten by k_conv2's final output.
    signed char* xq    = (signed char*)d_out;

    hipMemsetAsync(d_ws, 0, 4096, stream);
    hipMemsetAsync(d_out, 0, XQTOT, stream);   // zero padded borders of xq

    k_reduce<<<2080, 256, 0, stream>>>(x, w1, w2, scal, w8_1, w8_2);
    k_quantx<<<dim3(2, HH, NB), 256, 0, stream>>>(x, scal, xq);

    dim3 grid(WW / TCC, HH / TRR, NB);   // (8, 16, 16) = 2048 blocks
    k_conv1<<<grid, 256, 0, stream>>>(xq, w8_1, b1, scal, acc16);
    k_conv2<<<grid, 256, 0, stream>>>(x, acc16, w8_2, b2, b1, scal, out);
}

// Round 14
// 97.466 us; speedup vs baseline: 1.1783x; 1.1783x over previous
//
#include <hip/hip_runtime.h>
#include <math.h>

// Problem constants (B=16, C=64, H=W=128)
#define NB 16
#define CC 64
#define HH 128
#define WW 128
#define NPIX (NB*CC*HH*WW)       // 16777216
#define WELEM (CC*CC*9)          // 36864

// conv tiling: 8 rows x 16 cols output per tile, all 64 oc. halo 10x18.
#define TRR 8
#define TCC 16
#define HRR 10
#define HCC 18
#define HPX (HRR*HCC)            // 180 halo pixels
#define PL  (HH*WW)              // plane stride

// padded quantized-x tensor: [n][132 rows][130 cols][64 ic] int8
#define PYY 132
#define PXX 130
#define XQIMG (PYY*PXX*64)       // 1098240 B per image

// scal layout (dwords): s1 slots at [i*16], i=0..31 ; s2 slots at [512+i*32]
#define S2OFF 512

typedef __attribute__((ext_vector_type(4))) int   int32x4;
typedef __attribute__((ext_vector_type(8))) short short8_t;

// LDS activation layout (conv2): [pix][64B], 16B chunks XOR-swizzled.
__device__ __forceinline__ int lds_a(int pix, int q) {
    return pix * 64 + ((q ^ ((pix >> 1) & 3)) << 4);
}

__device__ __forceinline__ float read_s1(const unsigned* scal) {
    float m = 0.f;
    #pragma unroll
    for (int i = 0; i < 32; ++i) m = fmaxf(m, __uint_as_float(scal[i * 16]));
    return m + 1e-8f;
}

__device__ __forceinline__ float max4(float4 v) {
    return fmaxf(fmaxf(fabsf(v.x), fabsf(v.y)), fmaxf(fabsf(v.z), fabsf(v.w)));
}

// ---------------- kernel 1: absmax + weight quant + xq border zero ----------------
// blocks 0..2047: absmax over x; 2048..2079: weight quant; 2080..2095: xq borders.
__global__ __launch_bounds__(256) void k_reduce(const float* __restrict__ x,
                                                const float* __restrict__ w1,
                                                const float* __restrict__ w2,
                                                unsigned* __restrict__ scal,
                                                signed char* __restrict__ o1,
                                                signed char* __restrict__ o2,
                                                signed char* __restrict__ xq) {
    __shared__ float red[4];
    const int tid = threadIdx.x;
    if (blockIdx.x < 2048) {
        const float4* x4 = (const float4*)x;
        const int base = blockIdx.x * 2048 + tid;
        float4 v0 = x4[base];
        float4 v1 = x4[base + 256];
        float4 v2 = x4[base + 512];
        float4 v3 = x4[base + 768];
        float4 v4 = x4[base + 1024];
        float4 v5 = x4[base + 1280];
        float4 v6 = x4[base + 1536];
        float4 v7 = x4[base + 1792];
        float a0 = fmaxf(max4(v0), max4(v1));
        float a1 = fmaxf(max4(v2), max4(v3));
        float a2 = fmaxf(max4(v4), max4(v5));
        float a3 = fmaxf(max4(v6), max4(v7));
        float m = fmaxf(fmaxf(a0, a1), fmaxf(a2, a3));
        #pragma unroll
        for (int o = 32; o; o >>= 1) m = fmaxf(m, __shfl_down(m, o, 64));
        if ((tid & 63) == 0) red[tid >> 6] = m;
        __syncthreads();
        if (tid == 0) {
            float v = fmaxf(fmaxf(red[0], red[1]), fmaxf(red[2], red[3]));
            atomicMax(&scal[(blockIdx.x & 31) * 16], __float_as_uint(v));
        }
    } else if (blockIdx.x < 2080) {
        const int wb = blockIdx.x - 2048;          // 0..31
        const int ten = wb >> 4;                   // 0 = w1, 1 = w2
        const int sl  = wb & 15;                   // slice: 4 oc per block
        const float* __restrict__ w = ten ? w2 : w1;
        signed char* __restrict__ w8 = ten ? o2 : o1;

        const float4* w4 = (const float4*)w;
        float m = 0.f;
        #pragma unroll
        for (int k = 0; k < 9; ++k) {
            float4 a = w4[tid + (k * 4 + 0) * 256];
            float4 b = w4[tid + (k * 4 + 1) * 256];
            float4 c = w4[tid + (k * 4 + 2) * 256];
            float4 d = w4[tid + (k * 4 + 3) * 256];
            m = fmaxf(m, fmaxf(fmaxf(max4(a), max4(b)), fmaxf(max4(c), max4(d))));
        }
        #pragma unroll
        for (int o = 32; o; o >>= 1) m = fmaxf(m, __shfl_down(m, o, 64));
        if ((tid & 63) == 0) red[tid >> 6] = m;
        __syncthreads();
        float mx = fmaxf(fmaxf(red[0], red[1]), fmaxf(red[2], red[3]));
        // max|tanh(w)| == tanh(max|w|)  (tanh monotone, odd)
        float inv = 1.f / (tanhf(mx) + 1e-8f);

        #pragma unroll
        for (int j = 0; j < 9; ++j) {
            int i = sl * 2304 + j * 256 + tid;
            float wt = tanhf(w[i]) * inv;                 // [-1, 1]
            float r  = rintf((wt + 1.f) * 1.5f);          // 0..3 (round-half-even)
            int oc = i / 576, rem = i % 576, ic = rem / 9, tap = rem % 9;
            int lane2 = (oc & 15) | ((ic >> 4) << 4);
            w8[(((oc >> 4) * 9 + tap) * 64 + lane2) * 16 + (ic & 15)] =
                (signed char)(int)(2.f * r - 3.f);
        }
    } else {
        // zero xq borders for image n (interior is fully written by k_quantx)
        const int n = blockIdx.x - 2080;
        for (int t = tid; t < 776; t += 256) {
            int r, c;
            if (t < 520) {                         // rows 0,129,130,131 full
                int r4 = t / 130;
                r = (r4 == 0) ? 0 : 128 + r4;
                c = t - r4 * 130;
            } else {                               // rows 1..128, cols 0 & 129
                int u = t - 520;
                r = 1 + (u >> 1);
                c = (u & 1) ? 129 : 0;
            }
            int4* dst = (int4*)(xq + ((size_t)n * PYY + r) * (PXX * 64)
                                   + (size_t)c * 64);
            int4 z = {0, 0, 0, 0};
            dst[0] = z; dst[1] = z; dst[2] = z; dst[3] = z;
        }
    }
}

// ---------------- kernel 1b: quantize x -> padded pixel-major int8 ----------------
__global__ __launch_bounds__(256) void k_quantx(const float* __restrict__ x,
                                                const unsigned* __restrict__ scal,
                                                signed char* __restrict__ xq) {
    __shared__ signed char ldsA[64 * 68];
    __shared__ int ldsB[64 * 16];
    const int tid = threadIdx.x;
    const int n = blockIdx.z, y = blockIdx.y, s = blockIdx.x;
    const float inv_s1 = 1.f / read_s1(scal);

    {
        const int ic = tid >> 2, g = tid & 3;
        const float* __restrict__ src =
            x + (((size_t)n * CC + ic) * HH + y) * WW + s * 64 + g * 16;
        unsigned dw[4];
        #pragma unroll
        for (int q = 0; q < 4; ++q) {
            float4 v = *(const float4*)(src + q * 4);
            float e[4] = {v.x, v.y, v.z, v.w};
            unsigned d = 0;
            #pragma unroll
            for (int j = 0; j < 4; ++j) {
                int qq = (int)rintf(fminf(fmaxf(e[j] * inv_s1, -1.f), 1.f));
                d |= (unsigned)(qq & 255) << (8 * j);
            }
            dw[q] = d;
        }
        *(int4*)(ldsA + ic * 68 + g * 16) = *(const int4*)dw;
    }
    __syncthreads();
    #pragma unroll
    for (int i = 0; i < 4; ++i) {
        int idx = tid + i * 256;
        int d = idx & 15, p = idx >> 4;
        const signed char* a = ldsA + (d * 4) * 68 + p;
        unsigned b0 = (unsigned char)a[0];
        unsigned b1 = (unsigned char)a[68];
        unsigned b2 = (unsigned char)a[136];
        unsigned b3 = (unsigned char)a[204];
        ldsB[p * 16 + d] = (int)(b0 | (b1 << 8) | (b2 << 16) | (b3 << 24));
    }
    __syncthreads();
    signed char* dst = xq + ((size_t)n * PYY + (y + 1)) * (PXX * 64)
                          + (size_t)(1 + s * 64) * 64;
    ((int4*)dst)[tid] = ((const int4*)ldsB)[tid];
}

// ---------------- conv1: barrier-free streaming MFMA, XCD-swizzled ----------------
__global__ __launch_bounds__(256, 5) void k_conv1(
    const signed char* __restrict__ xq,
    const signed char* __restrict__ w8,
    const float* __restrict__ bias,       // b1 (for relu-max only)
    unsigned* __restrict__ scal,
    short* __restrict__ accout)
{
    __shared__ float redm[4];
    const int tid = threadIdx.x;
    // bijective XCD swizzle: nwg=2048, 256 per XCD chunk
    const int bid = blockIdx.x;
    const int swz = (bid & 7) * 256 + (bid >> 3);
    const int tx  = swz & 7;
    const int ty  = (swz >> 3) & 15;
    const int n   = swz >> 7;
    const int oy0 = ty * TRR;
    const int ox0 = tx * TCC;
    const float s1 = read_s1(scal);

    const int w     = tid >> 6;           // 0..3
    const int lane  = tid & 63;
    const int lq    = lane >> 4;
    const int lc    = lane & 15;
    const int rbase = w * 2;              // 2 rows per wave

    const signed char* __restrict__ A0 = xq + (size_t)n * XQIMG
        + ((size_t)(oy0 + rbase) * PXX + ox0 + lc) * 64 + lq * 16;
    const signed char* __restrict__ W0 = w8 + (size_t)lane * 16;

    int32x4 acc[2][4] = {};
    #pragma unroll 3
    for (int tap = 0; tap < 9; ++tap) {
        const int ky = tap / 3, kx = tap % 3;
        int32x4 b0 = *(const int32x4*)(W0 + (size_t)(0 * 9 + tap) * 1024);
        int32x4 b1 = *(const int32x4*)(W0 + (size_t)(1 * 9 + tap) * 1024);
        int32x4 b2 = *(const int32x4*)(W0 + (size_t)(2 * 9 + tap) * 1024);
        int32x4 b3 = *(const int32x4*)(W0 + (size_t)(3 * 9 + tap) * 1024);
        const signed char* ar = A0 + (ky * PXX + kx) * 64;
        #pragma unroll
        for (int j = 0; j < 2; ++j) {
            int32x4 a = *(const int32x4*)(ar + j * (PXX * 64));
            acc[j][0] = __builtin_amdgcn_mfma_i32_16x16x64_i8(a, b0, acc[j][0], 0, 0, 0);
            acc[j][1] = __builtin_amdgcn_mfma_i32_16x16x64_i8(a, b1, acc[j][1], 0, 0, 0);
            acc[j][2] = __builtin_amdgcn_mfma_i32_16x16x64_i8(a, b2, acc[j][2], 0, 0, 0);
            acc[j][3] = __builtin_amdgcn_mfma_i32_16x16x64_i8(a, b3, acc[j][3], 0, 0, 0);
        }
    }

    // epilogue: pixel-major int16 store + slotted atomic relu-max
    const float sc = s1 * (1.f / 3.f);
    float m2 = 0.f;
    #pragma unroll
    for (int j = 0; j < 2; ++j) {
        const int yy = oy0 + rbase + j;
        const size_t pbase = (((size_t)n * HH + yy) * WW + (ox0 + lq * 4)) * 64;
        #pragma unroll
        for (int g = 0; g < 4; ++g) {
            const float bo = bias[g * 16 + lc];
            #pragma unroll
            for (int e = 0; e < 4; ++e) {
                int v = acc[j][g][e];
                m2 = fmaxf(m2, sc * (float)v + bo);
                accout[pbase + (size_t)e * 64 + g * 16 + lc] = (short)v;
            }
        }
    }
    #pragma unroll
    for (int o = 32; o; o >>= 1) m2 = fmaxf(m2, __shfl_down(m2, o, 64));
    if (lane == 0) redm[w] = m2;
    __syncthreads();
    if (tid == 0) {
        float v = fmaxf(fmaxf(redm[0], redm[1]), fmaxf(redm[2], redm[3]));
        atomicMax(&scal[S2OFF + (swz & 7) * 32], __float_as_uint(v));
    }
}

// ---------------- conv2 helpers ----------------
__device__ __forceinline__ bool stage_load(const short* __restrict__ accin,
    int n, int oy0, int ox0, int sr, int scx, bool sact, short8_t ld[8]) {
    int y  = oy0 - 1 + sr;
    int xx = ox0 - 1 + scx;
    bool v = sact & (y >= 0) & (y < HH) & (xx >= 0) & (xx < WW);
    int yc = v ? y : 0, xc = v ? xx : 0;
    const short8_t* __restrict__ ap =
        (const short8_t*)(accin + (((size_t)n * HH + yc) * WW + xc) * 64);
    #pragma unroll
    for (int k = 0; k < 8; ++k) ld[k] = ap[k];
    return v;
}

__device__ __forceinline__ void binarize_store(signed char* sbuf, int tid,
    const short8_t ld[8], bool v, const float* __restrict__ b1v,
    float sc1, float half_s2) {
    unsigned pk[16];
    #pragma unroll
    for (int d = 0; d < 16; ++d) pk[d] = 0;
    if (v) {
        #pragma unroll
        for (int k = 0; k < 8; ++k) {
            short8_t sv = ld[k];
            float4 bA = *(const float4*)(b1v + k * 8);
            float4 bB = *(const float4*)(b1v + k * 8 + 4);
            float ba[8] = {bA.x, bA.y, bA.z, bA.w, bB.x, bB.y, bB.z, bB.w};
            #pragma unroll
            for (int e = 0; e < 8; ++e) {
                float fv = sc1 * (float)sv[e] + ba[e];
                if (fv >= half_s2) pk[2 * k + (e >> 2)] |= 1u << ((e & 3) * 8);
            }
        }
    }
    #pragma unroll
    for (int q = 0; q < 4; ++q) {
        int4 wv;
        wv.x = (int)pk[4 * q];     wv.y = (int)pk[4 * q + 1];
        wv.z = (int)pk[4 * q + 2]; wv.w = (int)pk[4 * q + 3];
        *(int4*)(sbuf + lds_a(tid, q)) = wv;
    }
}

__device__ __forceinline__ void conv2_mfma(const signed char* __restrict__ sbuf,
    const signed char* __restrict__ W0, int rbase, int lq, int lc,
    int32x4 acc[2][4]) {
    #pragma unroll 3
    for (int tap = 0; tap < 9; ++tap) {
        const int ky = tap / 3, kx = tap % 3;
        int32x4 b0 = *(const int32x4*)(W0 + (size_t)(0 * 9 + tap) * 1024);
        int32x4 b1 = *(const int32x4*)(W0 + (size_t)(1 * 9 + tap) * 1024);
        int32x4 b2 = *(const int32x4*)(W0 + (size_t)(2 * 9 + tap) * 1024);
        int32x4 b3 = *(const int32x4*)(W0 + (size_t)(3 * 9 + tap) * 1024);
        #pragma unroll
        for (int j = 0; j < 2; ++j) {
            int pix = (rbase + j + ky) * HCC + kx + lc;
            int32x4 a = *(const int32x4*)(sbuf + lds_a(pix, lq));
            acc[j][0] = __builtin_amdgcn_mfma_i32_16x16x64_i8(a, b0, acc[j][0], 0, 0, 0);
            acc[j][1] = __builtin_amdgcn_mfma_i32_16x16x64_i8(a, b1, acc[j][1], 0, 0, 0);
            acc[j][2] = __builtin_amdgcn_mfma_i32_16x16x64_i8(a, b2, acc[j][2], 0, 0, 0);
            acc[j][3] = __builtin_amdgcn_mfma_i32_16x16x64_i8(a, b3, acc[j][3], 0, 0, 0);
        }
    }
}

__device__ __forceinline__ void conv2_epi(float* __restrict__ out,
    const float* __restrict__ x, const float* __restrict__ bias, float sc,
    int n, int oy0, int ox0, int rbase, int lq, int lc,
    const int32x4 acc[2][4]) {
    const size_t imgbase = (size_t)n * CC * PL;
    #pragma unroll
    for (int j = 0; j < 2; ++j) {
        const int yy = oy0 + rbase + j;
        const int xb = ox0 + lq * 4;
        #pragma unroll
        for (int g = 0; g < 4; ++g) {
            const int oc = g * 16 + lc;
            const float bo = bias[oc];
            size_t p = imgbase + (size_t)oc * PL + yy * WW + xb;
            float4 xa = *(const float4*)(x + p);
            float4 r;
            r.x = sc * (float)acc[j][g][0] + bo + xa.x;
            r.y = sc * (float)acc[j][g][1] + bo + xa.y;
            r.z = sc * (float)acc[j][g][2] + bo + xa.z;
            r.w = sc * (float)acc[j][g][3] + bo + xa.w;
            *(float4*)(out + p) = r;
        }
    }
}

// ---------------- conv2: two-tile pipelined (stage t1 under MFMA t0) ------------
__global__ __launch_bounds__(256, 4) void k_conv2(
    const float* __restrict__ x,
    const short* __restrict__ accin,      // pixel-major [n][y][x][64]
    const signed char* __restrict__ w8,
    const float* __restrict__ bias,       // b2
    const float* __restrict__ b1v,        // b1 (dequant of acc)
    const unsigned* __restrict__ scal,
    float* __restrict__ out)
{
    __shared__ signed char sA0[HPX * 64] __attribute__((aligned(16)));
    __shared__ signed char sA1[HPX * 64] __attribute__((aligned(16)));

    const int tid = threadIdx.x;
    // bijective XCD swizzle: nwg=1024, 128 per XCD chunk
    const int bid = blockIdx.x;
    const int swz = (bid & 7) * 128 + (bid >> 3);
    const int tx  = swz & 7;
    const int typ = (swz >> 3) & 7;       // y tile-pair
    const int n   = swz >> 6;
    const int ox0 = tx * TCC;
    const int oyA = typ * 16;             // tile 0
    const int oyB = oyA + 8;              // tile 1

    const float s1 = read_s1(scal);
    float mx = 0.f;
    #pragma unroll
    for (int i = 0; i < 8; ++i) mx = fmaxf(mx, __uint_as_float(scal[S2OFF + i * 32]));
    const float s2v = mx + 1e-8f;
    const float half_s2 = 0.5f * s2v;
    const float sc1 = s1 * (1.f / 3.f);
    const float sc  = s2v * (1.f / 3.f);

    const int w     = tid >> 6;
    const int lane  = tid & 63;
    const int lq    = lane >> 4;
    const int lc    = lane & 15;
    const int rbase = w * 2;
    const int sr  = tid / HCC;
    const int scx = tid - sr * HCC;
    const bool sact = tid < HPX;
    const signed char* __restrict__ W0 = w8 + (size_t)lane * 16;

    short8_t ld[8];
    // stage tile 0
    bool v0 = stage_load(accin, n, oyA, ox0, sr, scx, sact, ld);
    if (sact) binarize_store(sA0, tid, ld, v0, b1v, sc1, half_s2);
    __syncthreads();

    // issue tile-1 loads NOW; they fly under MFMA(t0)
    bool v1 = stage_load(accin, n, oyB, ox0, sr, scx, sact, ld);

    {
        int32x4 acc[2][4] = {};
        conv2_mfma(sA0, W0, rbase, lq, lc, acc);
        if (sact) binarize_store(sA1, tid, ld, v1, b1v, sc1, half_s2);
        conv2_epi(out, x, bias, sc, n, oyA, ox0, rbase, lq, lc, acc);
    }
    __syncthreads();
    {
        int32x4 acc[2][4] = {};
        conv2_mfma(sA1, W0, rbase, lq, lc, acc);
        conv2_epi(out, x, bias, sc, n, oyB, ox0, rbase, lq, lc, acc);
    }
}

extern "C" void kernel_launch(void* const* d_in, const int* in_sizes, int n_in,
                              void* d_out, int out_size, void* d_ws, size_t ws_size,
                              hipStream_t stream) {
    const float* x  = (const float*)d_in[0];
    const float* w1 = (const float*)d_in[1];
    const float* b1 = (const float*)d_in[2];
    const float* w2 = (const float*)d_in[3];
    const float* b2 = (const float*)d_in[4];
    float* out = (float*)d_out;

    // ws layout
    unsigned*    scal  = (unsigned*)d_ws;                  // s1 slots [i*16], s2 [512+i*32]
    signed char* w8_1  = (signed char*)d_ws + 4096;        // 36864 B
    signed char* w8_2  = w8_1 + WELEM;                     // 36864 B
    short*       acc16 = (short*)((char*)d_ws + 131072);   // 33.55 MB pixel-major
    // xq lives in d_out's scratch space: written by k_reduce (borders) +
    // k_quantx (interior), read by k_conv1, overwritten by k_conv2's output.
    signed char* xq    = (signed char*)d_out;

    hipMemsetAsync(d_ws, 0, 4096, stream);

    k_reduce<<<2096, 256, 0, stream>>>(x, w1, w2, scal, w8_1, w8_2, xq);
    k_quantx<<<dim3(2, HH, NB), 256, 0, stream>>>(x, scal, xq);
    k_conv1<<<2048, 256, 0, stream>>>(xq, w8_1, b1, scal, acc16);
    k_conv2<<<1024, 256, 0, stream>>>(x, acc16, w8_2, b2, b1, scal, out);
}